// Round 1
// 685.540 us; speedup vs baseline: 1.2921x; 1.2921x over previous
//
#include <hip/hip_runtime.h>
#include <math.h>

// ---------------------------------------------------------------------------
// QFullResnetBlock: two quantum passes (13x 12-qubit sims + 1x 4-qubit sim per
// batch elem) + groupnorm/time-FiLM/swish glue + residual.
//
// 12-qubit sim layout (one 64-thread WAVE per (circuit ci, batch b)):
// Amplitude index amp (12 bits) = (lane << 6) | k :
//   bits 0..5  = k    (register-local, sr[64]/si[64])
//   bits 6..11 = lane (lane bit L = amp bit 6+L; exchange via __shfl_xor)
// Qubit w lives at amp bit (11-w).
//
// No LDS, no __syncthreads: every gate is register-local math or an in-wave
// shuffle. CRZ groups with thread-uniform controls are fused into small
// per-thread multiplier tables (all CRZs are diagonal and commute).
//
// Gate pattern per layer l, group j, m=0..3 (amp-bit positions):
//   crz/crx target bit pt = 4j + m, control bit pc = (4j + 8 + m) % 12
//   j=0: pt=m      (k bit, local pairs),  pc=8+m  (lane bit 2+m, uniform)
//   j=1: pt=4+m    (m<2: k bit; m>=2: lane bit m-2), pc=m (k bit, free skip)
//   j=2: pt=8+m    (lane bit 2+m, shuffle), pc=4+m (m<2: k bit; m>=2: lane)
// ---------------------------------------------------------------------------

#define PI_F 3.14159265358979323846f

// CRZ, control = k bit PC, target = k bit PT (compile-time skip on control)
template<int PC, int PT>
__device__ __forceinline__ void crz_kk(float cg, float sg, float* sr, float* si)
{
#pragma unroll
    for (int k = 0; k < 64; ++k) {
        if (!((k >> PC) & 1)) continue;
        float ss = ((k >> PT) & 1) ? sg : -sg;
        float r = sr[k], im = si[k];
        sr[k] = cg * r  - ss * im;
        si[k] = cg * im + ss * r;
    }
}

// CRZ, control = k bit PC, target = lane bit LT (sign hoisted per thread)
template<int PC, int LT>
__device__ __forceinline__ void crz_kl(float cg, float sg, float* sr, float* si,
                                       int lane)
{
    float ss = ((lane >> LT) & 1) ? sg : -sg;
#pragma unroll
    for (int k = 0; k < 64; ++k) {
        if (!((k >> PC) & 1)) continue;
        float r = sr[k], im = si[k];
        sr[k] = cg * r  - ss * im;
        si[k] = cg * im + ss * r;
    }
}

// CRX, control folded into (cg,sg) [identity when inactive], target = k bit PT
template<int PT>
__device__ __forceinline__ void crx_loc(float cg, float sg, float* sr, float* si)
{
#pragma unroll
    for (int k = 0; k < 64; ++k) {
        if ((k >> PT) & 1) continue;
        int p = k | (1 << PT);
        float r0 = sr[k], i0 = si[k], r1 = sr[p], i1 = si[p];
        sr[k] = cg * r0 + sg * i1;  si[k] = cg * i0 - sg * r1;
        sr[p] = cg * r1 + sg * i0;  si[p] = cg * i1 - sg * r0;
    }
}

// CRX, control = k bit PC, target = k bit PT
template<int PC, int PT>
__device__ __forceinline__ void crx_kk(float cg, float sg, float* sr, float* si)
{
#pragma unroll
    for (int k = 0; k < 64; ++k) {
        if (!((k >> PC) & 1) || ((k >> PT) & 1)) continue;
        int p = k | (1 << PT);
        float r0 = sr[k], i0 = si[k], r1 = sr[p], i1 = si[p];
        sr[k] = cg * r0 + sg * i1;  si[k] = cg * i0 - sg * r1;
        sr[p] = cg * r1 + sg * i0;  si[p] = cg * i1 - sg * r0;
    }
}

// CRX, control = k bit PC (compile-time skip), target = lane bit LT (shuffle)
template<int PC, int LT>
__device__ __forceinline__ void crx_sh_k(float cg, float sg, float* sr, float* si)
{
#pragma unroll
    for (int k = 0; k < 64; ++k) {
        if (!((k >> PC) & 1)) continue;
        float br = __shfl_xor(sr[k], 1 << LT, 64);
        float bi = __shfl_xor(si[k], 1 << LT, 64);
        float r = sr[k], im = si[k];
        sr[k] = cg * r  + sg * bi;
        si[k] = cg * im - sg * br;
    }
}

// CRX, control folded (thread-uniform), target = lane bit LT (shuffle, all k)
template<int LT>
__device__ __forceinline__ void crx_sh_all(float cg, float sg, float* sr, float* si)
{
#pragma unroll
    for (int k = 0; k < 64; ++k) {
        float br = __shfl_xor(sr[k], 1 << LT, 64);
        float bi = __shfl_xor(si[k], 1 << LT, 64);
        float r = sr[k], im = si[k];
        sr[k] = cg * r  + sg * bi;
        si[k] = cg * im - sg * br;
    }
}

// Fused j=0 CRZ group: gates m=0..3, ctrl = lane bit 2+m (thread-uniform),
// target = k bit m. Multiplier depends only on k&15; M[~t] = conj(M[t]).
__device__ __forceinline__ void crz_j0_fused(const float* a, float* sr, float* si,
                                             int lane)
{
    float gr[4], gi[4];
#pragma unroll
    for (int m = 0; m < 4; ++m) {
        bool cb = (lane >> (2 + m)) & 1;
        gr[m] = cb ? a[2 * m]     : 1.0f;
        gi[m] = cb ? a[2 * m + 1] : 0.0f;
    }
    // pair products with conjugate symmetry: store [t1t0]=00 and 01
    float u0 = gr[1] * gr[0], v0 = gi[1] * gi[0];
    float w0 = gr[1] * gi[0], z0 = gi[1] * gr[0];
    float p01r[2] = { u0 - v0, u0 + v0 };
    float p01i[2] = { -(w0 + z0), w0 - z0 };
    float u1 = gr[3] * gr[2], v1 = gi[3] * gi[2];
    float w1 = gr[3] * gi[2], z1 = gi[3] * gr[2];
    float p23r[2] = { u1 - v1, u1 + v1 };
    float p23i[2] = { -(w1 + z1), w1 - z1 };

    float Mr[8], Mi[8];
#pragma unroll
    for (int t = 0; t < 8; ++t) {
        const int t10 = t & 3, t2 = (t >> 2) & 1;
        float br = (t10 == 0 || t10 == 3) ? p01r[0] : p01r[1];
        float bi = (t10 == 0) ? p01i[0] : (t10 == 1) ? p01i[1]
                 : (t10 == 2) ? -p01i[1] : -p01i[0];
        float ar = p23r[t2], ai = p23i[t2];
        Mr[t] = ar * br - ai * bi;
        Mi[t] = ar * bi + ai * br;
    }
#pragma unroll
    for (int k = 0; k < 64; ++k) {
        const int t = k & 15;
        float mr = (t < 8) ? Mr[t] : Mr[15 - t];
        float mi = (t < 8) ? Mi[t] : -Mi[15 - t];
        float r = sr[k], im = si[k];
        sr[k] = mr * r  - mi * im;
        si[k] = mr * im + mi * r;
    }
}

// Fused j=2 CRZ group: gates m=0..3 (coeffs a[0..7] = layer base + 32):
//  m=0: ctrl k bit 4, sign lane bit 2 ; m=1: ctrl k bit 5, sign lane bit 3
//  m=2: ctrl lane bit 0, sign lane bit 4 ; m=3: ctrl lane bit 1, sign lane bit 5
// Multiplier depends only on k bits 4..5 -> 4-entry table.
__device__ __forceinline__ void crz_j2_fused(const float* a, float* sr, float* si,
                                             int lane)
{
    float s0p = ((lane >> 2) & 1) ? a[1] : -a[1];
    float s1p = ((lane >> 3) & 1) ? a[3] : -a[3];
    bool cb2 = lane & 1;
    float ss2 = ((lane >> 4) & 1) ? a[5] : -a[5];
    float g2r = cb2 ? a[4] : 1.0f, g2i = cb2 ? ss2 : 0.0f;
    bool cb3 = (lane >> 1) & 1;
    float ss3 = ((lane >> 5) & 1) ? a[7] : -a[7];
    float g3r = cb3 ? a[6] : 1.0f, g3i = cb3 ? ss3 : 0.0f;
    float Sr  = g2r * g3r - g2i * g3i;
    float Si_ = g2r * g3i + g2i * g3r;
    float Tr[4], Ti[4];
    Tr[0] = Sr;                        Ti[0] = Si_;
    Tr[1] = Sr * a[0] - Si_ * s0p;     Ti[1] = Sr * s0p + Si_ * a[0];
    Tr[2] = Sr * a[2] - Si_ * s1p;     Ti[2] = Sr * s1p + Si_ * a[2];
    Tr[3] = Tr[1] * a[2] - Ti[1] * s1p; Ti[3] = Tr[1] * s1p + Ti[1] * a[2];
#pragma unroll
    for (int k = 0; k < 64; ++k) {
        const int t = (k >> 4) & 3;
        float r = sr[k], im = si[k];
        sr[k] = Tr[t] * r  - Ti[t] * im;
        si[k] = Tr[t] * im + Ti[t] * r;
    }
}

__global__ void __launch_bounds__(64, 2)
qpass12_kernel(const float* __restrict__ inp, const float* __restrict__ cs,
               float* __restrict__ outp)
{
    const int lane = threadIdx.x;
    const int bx = blockIdx.x;
    const int ci = bx % 13;
    const int b  = bx / 13;
    const float* csc = cs + ci * 144;     // 72 gates * (cos,sin)
    const int ibase = b * 160 + ci * 3;   // (B,2,2,40) flat; sp stride 40

    // data angles: qubit w <- inp[b, w/3, (w%3)+3*ci]
    float cw[12], sw[12];
#pragma unroll
    for (int w = 0; w < 12; ++w) {
        float x = inp[ibase + (w / 3) * 40 + (w % 3)];
        __sincosf(0.5f * x, &sw[w], &cw[w]);
    }

    // product-state init: qubit w at amp bit 11-w
    // lane prefactor (qubits 0..5 at lane bits 5..0)
    float pref = 1.0f;
#pragma unroll
    for (int w = 0; w < 6; ++w)
        pref *= ((lane >> (5 - w)) & 1) ? sw[w] : cw[w];

    // k-bit tables: fb over k bits 0..2 (qubits 11,10,9), eb over 3..5 (8,7,6)
    float fb[8], eb[8];
#pragma unroll
    for (int t = 0; t < 8; ++t) {
        fb[t] = ((t & 1) ? sw[11] : cw[11]) * ((t & 2) ? sw[10] : cw[10]) *
                ((t & 4) ? sw[9] : cw[9]);
        eb[t] = pref * ((t & 1) ? sw[8] : cw[8]) * ((t & 2) ? sw[7] : cw[7]) *
                ((t & 4) ? sw[6] : cw[6]);
    }

    // phase (-i)^popc(amp): omega = (-i)^popc(lane), per-k part compile-time
    const int pl = __popc(lane) & 3;
    float oa = (pl == 0) ? 1.0f : (pl == 2) ? -1.0f : 0.0f;
    float ob = (pl == 1) ? -1.0f : (pl == 3) ? 1.0f : 0.0f;

    float sr[64], si[64];
#pragma unroll
    for (int k = 0; k < 64; ++k) {
        float v = eb[k >> 3] * fb[k & 7];
        const int q = __popc(k) & 3;
        if (q == 0)      { sr[k] =  v * oa; si[k] =  v * ob; }
        else if (q == 1) { sr[k] =  v * ob; si[k] = -v * oa; }
        else if (q == 2) { sr[k] = -v * oa; si[k] = -v * ob; }
        else             { sr[k] = -v * ob; si[k] =  v * oa; }
    }

#pragma unroll 1
    for (int l = 0; l < 3; ++l) {
        const float* a = csc + l * 48;

        // ---- group j=0 (i=11): tgt bits 0..3 (k), ctrl bits 8..11 (lane) ----
        crz_j0_fused(a, sr, si, lane);
        { bool cb = (lane >> 2) & 1;
          crx_loc<0>(cb ? a[ 8] : 1.0f, cb ? a[ 9] : 0.0f, sr, si); }
        { bool cb = (lane >> 3) & 1;
          crx_loc<1>(cb ? a[10] : 1.0f, cb ? a[11] : 0.0f, sr, si); }
        { bool cb = (lane >> 4) & 1;
          crx_loc<2>(cb ? a[12] : 1.0f, cb ? a[13] : 0.0f, sr, si); }
        { bool cb = (lane >> 5) & 1;
          crx_loc<3>(cb ? a[14] : 1.0f, cb ? a[15] : 0.0f, sr, si); }

        // ---- group j=1 (i=7): tgt bits 4..7, ctrl bits 0..3 (k, free) ----
        crz_kk<0, 4>(a[16], a[17], sr, si);
        crz_kk<1, 5>(a[18], a[19], sr, si);
        crz_kl<2, 0>(a[20], a[21], sr, si, lane);
        crz_kl<3, 1>(a[22], a[23], sr, si, lane);
        crx_kk<0, 4>(a[24], a[25], sr, si);
        crx_kk<1, 5>(a[26], a[27], sr, si);
        crx_sh_k<2, 0>(a[28], a[29], sr, si);
        crx_sh_k<3, 1>(a[30], a[31], sr, si);

        // ---- group j=2 (i=3): tgt bits 8..11 (lane), ctrl bits 4..7 ----
        crz_j2_fused(a + 32, sr, si, lane);
        crx_sh_k<4, 2>(a[40], a[41], sr, si);
        crx_sh_k<5, 3>(a[42], a[43], sr, si);
        { bool cb = lane & 1;
          crx_sh_all<4>(cb ? a[44] : 1.0f, cb ? a[45] : 0.0f, sr, si); }
        { bool cb = (lane >> 1) & 1;
          crx_sh_all<5>(cb ? a[46] : 1.0f, cb ? a[47] : 0.0f, sr, si); }
    }

    // expectation values <Z_w>; reuse sr[] as probability array
    float total = 0.0f;
#pragma unroll
    for (int k = 0; k < 64; ++k) {
        sr[k] = sr[k] * sr[k] + si[k] * si[k];
        total += sr[k];
    }
    float v12[12];
#pragma unroll
    for (int w = 0; w < 6; ++w)
        v12[w] = ((lane >> (5 - w)) & 1) ? -total : total;
#pragma unroll
    for (int w = 6; w < 12; ++w) {
        float acc = 0.0f;
#pragma unroll
        for (int k = 0; k < 64; ++k)
            acc += ((k >> (11 - w)) & 1) ? -sr[k] : sr[k];
        v12[w] = acc;
    }
    // in-wave butterfly reduce (64 lanes)
#pragma unroll
    for (int w = 0; w < 12; ++w) {
#pragma unroll
        for (int off = 1; off < 64; off <<= 1)
            v12[w] += __shfl_xor(v12[w], off, 64);
    }
    if (lane == 0) {
#pragma unroll
        for (int w = 0; w < 12; ++w)
            outp[ibase + (w / 3) * 40 + (w % 3)] = v12[w];
    }
}

__global__ void q4_kernel(const float* __restrict__ inp,
                          const float* __restrict__ cs4,
                          float* __restrict__ outp)
{
    int b = blockIdx.x * blockDim.x + threadIdx.x;
    if (b >= 1024) return;
    float cw[4], sw[4];
#pragma unroll
    for (int j = 0; j < 4; ++j) {
        float x = inp[(b * 4 + j) * 40 + 39];
        __sincosf(0.5f * x, &sw[j], &cw[j]);
    }
    float sr[16], si[16];
#pragma unroll
    for (int k = 0; k < 16; ++k) {
        float v = 1.0f;
#pragma unroll
        for (int j = 0; j < 4; ++j)
            v *= ((k >> (3 - j)) & 1) ? sw[j] : cw[j];
        int ph = __popc(k) & 3;
        sr[k] = (ph == 0) ? v : (ph == 2) ? -v : 0.0f;
        si[k] = (ph == 1) ? -v : (ph == 3) ? v : 0.0f;
    }
#pragma unroll
    for (int l = 0; l < 4; ++l) {
        // RX(theta[4l+w]) on qubit w (bit 3-w)
#pragma unroll
        for (int w = 0; w < 4; ++w) {
            float cg = cs4[2 * (4 * l + w)], sg = cs4[2 * (4 * l + w) + 1];
            const int m = 1 << (3 - w);
#pragma unroll
            for (int k = 0; k < 16; ++k) {
                if (k & m) continue;
                int p2 = k | m;
                float r0 = sr[k], i0 = si[k], r1 = sr[p2], i1 = si[p2];
                sr[k]  = cg * r0 + sg * i1;  si[k]  = cg * i0 - sg * r1;
                sr[p2] = cg * r1 + sg * i0;  si[p2] = cg * i1 - sg * r0;
            }
        }
        // CNOT (0,1),(1,2),(2,3),(3,0)
#pragma unroll
        for (int e = 0; e < 4; ++e) {
            const int cq = e, tq = (e + 1) & 3;
            const int pcb = 1 << (3 - cq), ptb = 1 << (3 - tq);
#pragma unroll
            for (int k = 0; k < 16; ++k) {
                if (!(k & pcb)) continue;
                if (k & ptb) continue;
                int p2 = k | ptb;
                float tr = sr[k], ti = si[k];
                sr[k] = sr[p2]; si[k] = si[p2];
                sr[p2] = tr;    si[p2] = ti;
            }
        }
    }
    float p[16];
#pragma unroll
    for (int k = 0; k < 16; ++k) p[k] = sr[k] * sr[k] + si[k] * si[k];
#pragma unroll
    for (int j = 0; j < 4; ++j) {
        float z = 0.0f;
#pragma unroll
        for (int k = 0; k < 16; ++k)
            z += ((k >> (3 - j)) & 1) ? -p[k] : p[k];
        outp[(b * 4 + j) * 40 + 39] = z;
    }
}

__global__ void prep_kernel(const float* __restrict__ q12,
                            const float* __restrict__ q4,
                            float* __restrict__ cs12,
                            float* __restrict__ cs4)
{
    int idx = blockIdx.x * 256 + threadIdx.x;
    if (idx < 26 * 72) {
        // gate angle = 2*pi*p, half-angle = pi*p
        float s, c;
        sincosf(PI_F * q12[idx], &s, &c);
        cs12[2 * idx]     = c;
        cs12[2 * idx + 1] = s;
    }
    if (idx < 16) {
        float s, c;
        sincosf(0.5f * q4[idx], &s, &c);
        cs4[2 * idx]     = c;
        cs4[2 * idx + 1] = s;
    }
}

__global__ void tmlp_kernel(const float* __restrict__ emb,
                            const float* __restrict__ W,
                            const float* __restrict__ bias,
                            float* __restrict__ t)
{
    __shared__ float se[128];
    int b = blockIdx.x, tid = threadIdx.x;
    float e = emb[b * 128 + tid];
    se[tid] = e / (1.0f + __expf(-e));
    __syncthreads();
    if (tid < 80) {
        float acc = bias[tid];
        for (int k = 0; k < 128; ++k) acc += se[k] * W[k * 80 + tid];
        t[b * 80 + tid] = acc;
    }
}

__global__ void gn0_kernel(const float* __restrict__ h, const float* __restrict__ t,
                           const float* __restrict__ sc, const float* __restrict__ bi,
                           float* __restrict__ outp)
{
    __shared__ float v[160];
    __shared__ float mu[10], rstd[10];
    int b = blockIdx.x, tid = threadIdx.x;
    if (tid < 160) v[tid] = h[b * 160 + tid];
    __syncthreads();
    if (tid < 10) {
        float s1 = 0.0f, s2 = 0.0f;
#pragma unroll
        for (int sp = 0; sp < 4; ++sp)
#pragma unroll
            for (int k = 0; k < 4; ++k) {
                float x = v[sp * 40 + tid * 4 + k];
                s1 += x; s2 += x * x;
            }
        float m = s1 * (1.0f / 16.0f);
        float var = s2 * (1.0f / 16.0f) - m * m;
        mu[tid] = m; rstd[tid] = rsqrtf(var + 1e-6f);
    }
    __syncthreads();
    if (tid < 160) {
        int ch = tid % 40;
        int g = ch >> 2;
        float hn = (v[tid] - mu[g]) * rstd[g] * sc[ch] + bi[ch];
        float scale = t[b * 80 + ch], shift = t[b * 80 + 40 + ch];
        float z = hn * (1.0f + scale) + shift;
        outp[b * 160 + tid] = z / (1.0f + __expf(-z));
    }
}

__global__ void gn1_kernel(const float* __restrict__ h, const float* __restrict__ x,
                           const float* __restrict__ sc, const float* __restrict__ bi,
                           float* __restrict__ outp)
{
    __shared__ float v[160];
    __shared__ float mu[10], rstd[10];
    int b = blockIdx.x, tid = threadIdx.x;
    if (tid < 160) v[tid] = h[b * 160 + tid];
    __syncthreads();
    if (tid < 10) {
        float s1 = 0.0f, s2 = 0.0f;
#pragma unroll
        for (int sp = 0; sp < 4; ++sp)
#pragma unroll
            for (int k = 0; k < 4; ++k) {
                float xx = v[sp * 40 + tid * 4 + k];
                s1 += xx; s2 += xx * xx;
            }
        float m = s1 * (1.0f / 16.0f);
        float var = s2 * (1.0f / 16.0f) - m * m;
        mu[tid] = m; rstd[tid] = rsqrtf(var + 1e-6f);
    }
    __syncthreads();
    if (tid < 160) {
        int ch = tid % 40;
        int g = ch >> 2;
        float hn = (v[tid] - mu[g]) * rstd[g] * sc[ch] + bi[ch];
        float sws = hn / (1.0f + __expf(-hn));
        outp[b * 160 + tid] = x[b * 160 + tid] + sws;
    }
}

extern "C" void kernel_launch(void* const* d_in, const int* in_sizes, int n_in,
                              void* d_out, int out_size, void* d_ws, size_t ws_size,
                              hipStream_t stream)
{
    const float* x    = (const float*)d_in[0];
    const float* temb = (const float*)d_in[1];
    const float* q12  = (const float*)d_in[2];
    const float* q4   = (const float*)d_in[3];
    const float* gn0s = (const float*)d_in[4];
    const float* gn0b = (const float*)d_in[5];
    const float* gn1s = (const float*)d_in[6];
    const float* gn1b = (const float*)d_in[7];
    const float* tw   = (const float*)d_in[8];
    const float* tb   = (const float*)d_in[9];
    float* out = (float*)d_out;

    float* ws   = (float*)d_ws;
    float* cs12 = ws;               // 26*72*2   = 3744
    float* cs4  = cs12 + 3744;      // 32
    float* tbuf = cs4 + 32;         // 1024*80   = 81920
    float* A    = tbuf + 81920;     // 1024*160  = 163840 (raw qpass out)
    float* Bf   = A + 163840;       // 1024*160  = 163840 (gn0 out / qpass2 in)

    prep_kernel<<<8, 256, 0, stream>>>(q12, q4, cs12, cs4);
    tmlp_kernel<<<1024, 128, 0, stream>>>(temb, tw, tb, tbuf);

    // pass 1
    qpass12_kernel<<<13312, 64, 0, stream>>>(x, cs12, A);
    q4_kernel<<<16, 64, 0, stream>>>(x, cs4, A);
    gn0_kernel<<<1024, 160, 0, stream>>>(A, tbuf, gn0s, gn0b, Bf);

    // pass 2
    qpass12_kernel<<<13312, 64, 0, stream>>>(Bf, cs12 + 13 * 144, A);
    q4_kernel<<<16, 64, 0, stream>>>(Bf, cs4, A);
    gn1_kernel<<<1024, 160, 0, stream>>>(A, x, gn1s, gn1b, out);
}